// Round 5
// baseline (481.955 us; speedup 1.0000x reference)
//
#include <hip/hip_runtime.h>
#include <hip/hip_bf16.h>

#define DIM    256
#define HEADS  8
#define DH     64
#define DPG    32
#define KNB    32
#define INNER  512
#define EPS    1e-5f

// ws float offsets
#define WS_SUMB 0         // f32 [4][256] banked channel sums
#define WS_SSQB 1024      // f32 [4][256] banked channel sq-sums
#define WS_WF   2048      // bf16 [3][8][64][32] folded weights  -> 24576 floats
#define WS_QB   26624     // f32  [3][8][64] folded biases       -> 1536 floats
#define WS_WT   28160     // bf16 [256][512] WoutT               -> 65536 floats (end 93696 floats = 375KB)

typedef float f32x4  __attribute__((ext_vector_type(4)));
typedef short bf16x8 __attribute__((ext_vector_type(8)));

__device__ __forceinline__ unsigned short f2bf(float f){
    unsigned u = __float_as_uint(f);
    u += 0x7fffu + ((u >> 16) & 1u);          // RNE
    return (unsigned short)(u >> 16);
}
__device__ __forceinline__ unsigned packbf(float a, float b){
    union { __hip_bfloat162 h; unsigned u; } c;
    c.h = __float22bfloat162_rn(make_float2(a, b));   // v_cvt_pk_bf16_f32 (RNE)
    return c.u;
}
__device__ __forceinline__ bf16x8 pack8(f32x4 a, f32x4 b){
    union { unsigned u[4]; bf16x8 v; } r;
    r.u[0] = packbf(a[0], a[1]); r.u[1] = packbf(a[2], a[3]);
    r.u[2] = packbf(b[0], b[1]); r.u[3] = packbf(b[2], b[3]);
    return r.v;
}

// XOR-swizzled LDS index maps (shorts), 8-short (16B) granules.
// q/k/vT: 32 rows x 64 cols, stride 64. swz=(row^(row>>2))&7 spreads scalar
// writes (g-groups) across all 8 granule offsets -> 2-way max; b128 reads
// stay balanced (8 lanes per 4-bank set).
#define QKSWZ(row, col) ((row) * 64 + ((col) ^ ((((row) ^ ((row) >> 2)) & 7) << 3)))
// ao: 32 rows x 512 cols, stride 512 (1KB rows == bank-aligned), row-XOR granule.
#define AOSWZ(row, col) ((row) * 512 + ((col) ^ (((row) & 7) << 3)))

// ---------------- BN statistics (float4, 4-deep ILP, banked atomics) --------------
__global__ __launch_bounds__(256) void bn_stats_k(const f32x4* __restrict__ x4,
                                                  float* __restrict__ ws, int n4) {
    __shared__ f32x4 rs[4][64], rss[4][64];
    const int tid = blockIdx.x * 256 + threadIdx.x;
    const int stride = gridDim.x * 256;
    f32x4 s  = {0.f, 0.f, 0.f, 0.f};
    f32x4 ss = {0.f, 0.f, 0.f, 0.f};
    int f = tid;
    const int nloop = n4 / (4 * stride);
    for (int i = 0; i < nloop; ++i) {          // 4 loads in flight per wave
        f32x4 v0 = x4[f];
        f32x4 v1 = x4[f + stride];
        f32x4 v2 = x4[f + 2 * stride];
        f32x4 v3 = x4[f + 3 * stride];
        f += 4 * stride;
        s += v0; ss += v0 * v0;
        s += v1; ss += v1 * v1;
        s += v2; ss += v2 * v2;
        s += v3; ss += v3 * v3;
    }
    for (; f < n4; f += stride) { f32x4 v = x4[f]; s += v; ss += v * v; }
    int c4 = threadIdx.x & 63, wv = threadIdx.x >> 6;
    rs[wv][c4] = s; rss[wv][c4] = ss;
    __syncthreads();
    const float* rsf  = (const float*)rs;
    const float* rssf = (const float*)rss;
    int ch = threadIdx.x;                      // channel = ch (flat view)
    float S = rsf[ch]  + rsf[256 + ch]  + rsf[512 + ch]  + rsf[768 + ch];
    float Q = rssf[ch] + rssf[256 + ch] + rssf[512 + ch] + rssf[768 + ch];
    int bank = (blockIdx.x & 3) * 256;
    atomicAdd(&ws[WS_SUMB + bank + ch], S);
    atomicAdd(&ws[WS_SSQB + bank + ch], Q);
}

// ---------------- Wout transpose to bf16 (64x64 LDS tile, coalesced uint4 writes) ----
__global__ __launch_bounds__(256) void wt_k(const float* __restrict__ Wout, float* __restrict__ ws) {
    __shared__ unsigned short tile[64][65];
    const int k0 = blockIdx.x * 64, n0 = blockIdx.y * 64;
    const int t = threadIdx.x;
    #pragma unroll
    for (int i = 0; i < 16; ++i) {
        int e = t + 256 * i;
        int kk = e >> 6, nn = e & 63;
        tile[kk][nn] = f2bf(Wout[(k0 + kk) * DIM + n0 + nn]);
    }
    __syncthreads();
    unsigned short* wt = (unsigned short*)(ws + WS_WT);
    #pragma unroll
    for (int i = 0; i < 2; ++i) {
        int f = t + 256 * i;               // 0..511
        int nn = f >> 3, kc = f & 7;
        union { unsigned short s[8]; uint4 u; } pk;
        #pragma unroll
        for (int j = 0; j < 8; ++j) pk.s[j] = tile[kc * 8 + j][nn];
        *(uint4*)(wt + (size_t)(n0 + nn) * INNER + k0 + kc * 8) = pk.u;
    }
}

// ------- BN finalize + fold into QKV weights/biases (coalesced, LDS-staged) --------
__global__ __launch_bounds__(256) void fold_k(const float* __restrict__ Wq,
                                              const float* __restrict__ Wk,
                                              const float* __restrict__ Wv,
                                              const float* __restrict__ gam,
                                              const float* __restrict__ bet,
                                              float* __restrict__ ws, float inv_n) {
    __shared__ float wl[64][33];
    __shared__ float scs[DPG], shs[DPG];
    const int m = blockIdx.x, h = blockIdx.y, t = threadIdx.x;
    const float* W = (m == 0 ? Wq : (m == 1 ? Wk : Wv)) + h * DH * DPG;
    if (t < DPG) {                             // per-head BN finalize (redundant x3, cheap)
        int c = h * DPG + t;
        float S = ws[WS_SUMB + c] + ws[WS_SUMB + 256 + c] + ws[WS_SUMB + 512 + c] + ws[WS_SUMB + 768 + c];
        float Q = ws[WS_SSQB + c] + ws[WS_SSQB + 256 + c] + ws[WS_SSQB + 512 + c] + ws[WS_SSQB + 768 + c];
        float mean = S * inv_n;
        float var  = Q * inv_n - mean * mean;
        float sc   = gam[c] * rsqrtf(var + EPS);
        scs[t] = sc;
        shs[t] = bet[c] - mean * sc;
    }
    #pragma unroll
    for (int i = 0; i < 8; ++i) {
        int e = t + 256 * i;               // 0..2047 coalesced
        wl[e >> 5][e & 31] = W[e];
    }
    __syncthreads();
    const float qsc = (m == 0) ? 0.125f : 1.f;   // dim_head^-0.5 folded into q
    unsigned short* wf = (unsigned short*)(ws + WS_WF) + (m * HEADS + h) * DH * DPG;
    {
        int o = t >> 2, c0 = (t & 3) * 8;
        union { unsigned short s[8]; uint4 u; } pk;
        #pragma unroll
        for (int j = 0; j < 8; ++j) pk.s[j] = f2bf(wl[o][c0 + j] * scs[c0 + j] * qsc);
        *(uint4*)(wf + o * DPG + c0) = pk.u;
    }
    if (t < DH) {
        float bias = 0.f;
        #pragma unroll
        for (int c = 0; c < DPG; ++c) bias += shs[c] * wl[t][c];
        ws[WS_QB + (m * HEADS + h) * DH + t] = bias * qsc;
    }
}

// ---------------- fused BN + QKV + attention + output GEMM (all MFMA) ----------------
// grid = npts (4096), block = 256 (4 waves). Wave w handles heads {w, w+4}.
// V computed AFTER dots/softmax so vT reuses k's LDS, probs reuse q's:
// per-wave LDS = 8KB, block = 32KB -> 5 blocks/CU (160KB exactly), 20 waves/CU.
// MFMA 16x16x32: A/B frag lane&15 = row, lane>>4 = k-octet; D col=lane&15, row=(lane>>4)*4+reg.
__global__ __launch_bounds__(256, 5) void attn_fused(const float* __restrict__ x,
                                                     const float* __restrict__ ws,
                                                     const float* __restrict__ bout,
                                                     float* __restrict__ out) {
    __shared__ __align__(16) unsigned short lds[16384];   // 32768 B

    const int t = threadIdx.x;
    const int w = t >> 6, L = t & 63;
    const int lr = L & 15, g = L >> 4;
    const long long rb = (long long)blockIdx.x * KNB;

    unsigned short* qsm = lds + w * 2048;            // [32][64] swizzled; probs reuse
    unsigned short* ksm = lds + 8192 + w * 2048;     // [32][64] swizzled; vT reuses
    unsigned short* psm = qsm;
    unsigned short* vtm = ksm;                       // vT[o][j] as [o&31][(o>>5)*32+j]
    const unsigned short* wfb = (const unsigned short*)(ws + WS_WF);
    const unsigned short* WT  = (const unsigned short*)(ws + WS_WT);

    // preload x fragments for both head-slots (hides HBM latency under hs=0)
    bf16x8 xa[2][2];
    #pragma unroll
    for (int hs = 0; hs < 2; ++hs)
        #pragma unroll
        for (int it = 0; it < 2; ++it) {
            const float* xp = x + (rb + it * 16 + lr) * DIM + (w + hs * 4) * DPG + g * 8;
            xa[hs][it] = pack8(*(const f32x4*)xp, *(const f32x4*)(xp + 4));
        }

    f32x4 av[2][2][4];                               // [head-slot][i-tile][o-tile]

    #pragma unroll
    for (int hs = 0; hs < 2; ++hs) {
        const int h = w + hs * 4;

        // ---- Q,K via MFMA (bias in acc init), store as [row][d] swizzled
        #pragma unroll
        for (int m = 0; m < 2; ++m) {
            unsigned short* dst = m ? ksm : qsm;
            #pragma unroll
            for (int ot = 0; ot < 4; ++ot) {
                const int o = ot * 16 + lr;
                bf16x8 wf = *(const bf16x8*)(wfb + ((m * HEADS + h) * DH + o) * DPG + g * 8);
                float bv = ws[WS_QB + (m * HEADS + h) * DH + o];
                #pragma unroll
                for (int it = 0; it < 2; ++it) {
                    f32x4 c = {bv, bv, bv, bv};
                    c = __builtin_amdgcn_mfma_f32_16x16x32_bf16(xa[hs][it], wf, c, 0, 0, 0);
                    unsigned u01 = packbf(c[0], c[1]);
                    unsigned u23 = packbf(c[2], c[3]);
                    const int r0 = it * 16 + g * 4;
                    dst[QKSWZ(r0 + 0, o)] = (unsigned short)u01;
                    dst[QKSWZ(r0 + 1, o)] = (unsigned short)(u01 >> 16);
                    dst[QKSWZ(r0 + 2, o)] = (unsigned short)u23;
                    dst[QKSWZ(r0 + 3, o)] = (unsigned short)(u23 >> 16);
                }
            }
        }

        // ---- dots = q @ k^T  (D: col = j, row = i)
        f32x4 dt[2][2];
        #pragma unroll
        for (int it = 0; it < 2; ++it)
            #pragma unroll
            for (int jt = 0; jt < 2; ++jt) dt[it][jt] = (f32x4){0.f, 0.f, 0.f, 0.f};
        #pragma unroll
        for (int ksp = 0; ksp < 2; ++ksp) {
            bf16x8 qa[2], kb[2];
            #pragma unroll
            for (int it = 0; it < 2; ++it)
                qa[it] = *(const bf16x8*)(qsm + QKSWZ(it * 16 + lr, ksp * 32 + g * 8));
            #pragma unroll
            for (int jt = 0; jt < 2; ++jt)
                kb[jt] = *(const bf16x8*)(ksm + QKSWZ(jt * 16 + lr, ksp * 32 + g * 8));
            #pragma unroll
            for (int it = 0; it < 2; ++it)
                #pragma unroll
                for (int jt = 0; jt < 2; ++jt)
                    dt[it][jt] = __builtin_amdgcn_mfma_f32_16x16x32_bf16(qa[it], kb[jt], dt[it][jt], 0, 0, 0);
        }

        // ---- softmax over j: local pair + xor-reduce across the 16-lane col group
        #pragma unroll
        for (int it = 0; it < 2; ++it)
            #pragma unroll
            for (int r = 0; r < 4; ++r) {
                float m0 = fmaxf(dt[it][0][r], dt[it][1][r]);
                m0 = fmaxf(m0, __shfl_xor(m0, 1, 64));
                m0 = fmaxf(m0, __shfl_xor(m0, 2, 64));
                m0 = fmaxf(m0, __shfl_xor(m0, 4, 64));
                m0 = fmaxf(m0, __shfl_xor(m0, 8, 64));
                float e0 = __expf(dt[it][0][r] - m0);
                float e1 = __expf(dt[it][1][r] - m0);
                float s = e0 + e1;
                s += __shfl_xor(s, 1, 64);
                s += __shfl_xor(s, 2, 64);
                s += __shfl_xor(s, 4, 64);
                s += __shfl_xor(s, 8, 64);
                float inv = 1.f / s;
                int row = it * 16 + g * 4 + r;
                unsigned up = packbf(e0 * inv, e1 * inv);
                psm[QKSWZ(row, lr)]      = (unsigned short)up;
                psm[QKSWZ(row, lr + 16)] = (unsigned short)(up >> 16);
            }

        // ---- V via MFMA (k dead after dots; xa still live) -> vT in ksm space
        #pragma unroll
        for (int ot = 0; ot < 4; ++ot) {
            const int o = ot * 16 + lr;
            bf16x8 wf = *(const bf16x8*)(wfb + ((2 * HEADS + h) * DH + o) * DPG + g * 8);
            float bv = ws[WS_QB + (2 * HEADS + h) * DH + o];
            #pragma unroll
            for (int it = 0; it < 2; ++it) {
                f32x4 c = {bv, bv, bv, bv};
                c = __builtin_amdgcn_mfma_f32_16x16x32_bf16(xa[hs][it], wf, c, 0, 0, 0);
                uint2 u;                      // vT[o][j..j+3]
                u.x = packbf(c[0], c[1]);
                u.y = packbf(c[2], c[3]);
                *(uint2*)(vtm + QKSWZ(o & 31, (o >> 5) * 32 + it * 16 + g * 4)) = u;
            }
        }

        // ---- AV: A = probs[i][j], B = vT[o][j]
        #pragma unroll
        for (int it = 0; it < 2; ++it) {
            bf16x8 pa = *(const bf16x8*)(psm + QKSWZ(it * 16 + lr, g * 8));
            #pragma unroll
            for (int ot = 0; ot < 4; ++ot) {
                bf16x8 vb = *(const bf16x8*)(vtm + QKSWZ((ot & 1) * 16 + lr, (ot >> 1) * 32 + g * 8));
                f32x4 c = {0.f, 0.f, 0.f, 0.f};
                av[hs][it][ot] = __builtin_amdgcn_mfma_f32_16x16x32_bf16(pa, vb, c, 0, 0, 0);
            }
        }
    }

    // ---- gather full-point ao[32][512] in LDS (av held in regs across barrier)
    __syncthreads();
    unsigned short* aos = lds;
    #pragma unroll
    for (int hs = 0; hs < 2; ++hs)
        #pragma unroll
        for (int it = 0; it < 2; ++it)
            #pragma unroll
            for (int ot = 0; ot < 4; ++ot)
                #pragma unroll
                for (int r = 0; r < 4; ++r)
                    aos[AOSWZ(it * 16 + g * 4 + r, (w + hs * 4) * 64 + ot * 16 + lr)]
                        = f2bf(av[hs][it][ot][r]);
    __syncthreads();

    // ---- output GEMM: out[32x256] = ao[32x512] @ WoutT^T + bout. Wave w: cols w*64..+63.
    f32x4 oacc[2][4];
    #pragma unroll
    for (int n4 = 0; n4 < 4; ++n4) {
        float bv = bout[(w * 4 + n4) * 16 + lr];
        oacc[0][n4] = (f32x4){bv, bv, bv, bv};
        oacc[1][n4] = (f32x4){bv, bv, bv, bv};
    }
    #pragma unroll 4
    for (int ksp = 0; ksp < 16; ++ksp) {
        bf16x8 a0 = *(const bf16x8*)(aos + AOSWZ(lr, ksp * 32 + g * 8));
        bf16x8 a1 = *(const bf16x8*)(aos + AOSWZ(16 + lr, ksp * 32 + g * 8));
        #pragma unroll
        for (int n4 = 0; n4 < 4; ++n4) {
            const int n = (w * 4 + n4) * 16 + lr;
            bf16x8 bvv = *(const bf16x8*)(WT + (size_t)n * INNER + ksp * 32 + g * 8);
            oacc[0][n4] = __builtin_amdgcn_mfma_f32_16x16x32_bf16(a0, bvv, oacc[0][n4], 0, 0, 0);
            oacc[1][n4] = __builtin_amdgcn_mfma_f32_16x16x32_bf16(a1, bvv, oacc[1][n4], 0, 0, 0);
        }
    }
    #pragma unroll
    for (int it = 0; it < 2; ++it)
        #pragma unroll
        for (int n4 = 0; n4 < 4; ++n4)
            #pragma unroll
            for (int r = 0; r < 4; ++r)
                out[(rb + it * 16 + g * 4 + r) * DIM + (w * 4 + n4) * 16 + lr] = oacc[it][n4][r];
}

extern "C" void kernel_launch(void* const* d_in, const int* in_sizes, int n_in,
                              void* d_out, int out_size, void* d_ws, size_t ws_size,
                              hipStream_t stream) {
    const float* x  = (const float*)d_in[0];
    const float* g  = (const float*)d_in[1];
    const float* b  = (const float*)d_in[2];
    const float* wq = (const float*)d_in[3];
    const float* wk = (const float*)d_in[4];
    const float* wv = (const float*)d_in[5];
    const float* wo = (const float*)d_in[6];
    const float* bo = (const float*)d_in[7];
    float* ws = (float*)d_ws;

    int rows = in_sizes[0] / DIM;       // 131072
    int npts = rows / KNB;              // 4096

    hipMemsetAsync(d_ws, 0, 8192, stream);
    wt_k<<<dim3(INNER / 64, DIM / 64), 256, 0, stream>>>(wo, ws);
    bn_stats_k<<<1024, 256, 0, stream>>>((const f32x4*)x, ws, rows * (DIM / 4));
    fold_k<<<dim3(3, HEADS), 256, 0, stream>>>(wq, wk, wv, g, b, ws, 1.0f / (float)rows);
    attn_fused<<<npts, 256, 0, stream>>>(x, ws, bo, (float*)d_out);
}

// Round 6
// 424.109 us; speedup vs baseline: 1.1364x; 1.1364x over previous
//
#include <hip/hip_runtime.h>
#include <hip/hip_bf16.h>

#define DIM    256
#define HEADS  8
#define DH     64
#define DPG    32
#define KNB    32
#define INNER  512
#define EPS    1e-5f

// ws float offsets
#define WS_SUMB 0         // f32 [4][256] banked channel sums
#define WS_SSQB 1024      // f32 [4][256] banked channel sq-sums
#define WS_WF   2048      // bf16 [3][8][64][32] folded weights  -> 24576 floats
#define WS_QB   26624     // f32  [3][8][64] folded biases       -> 1536 floats
#define WS_WT   28160     // bf16 [256][512] WoutT               -> 65536 floats (end 93696 floats = 375KB)

typedef float f32x4  __attribute__((ext_vector_type(4)));
typedef short bf16x8 __attribute__((ext_vector_type(8)));

__device__ __forceinline__ unsigned short f2bf(float f){
    unsigned u = __float_as_uint(f);
    u += 0x7fffu + ((u >> 16) & 1u);          // RNE
    return (unsigned short)(u >> 16);
}
__device__ __forceinline__ unsigned packbf(float a, float b){
    union { __hip_bfloat162 h; unsigned u; } c;
    c.h = __float22bfloat162_rn(make_float2(a, b));   // v_cvt_pk_bf16_f32 (RNE)
    return c.u;
}
__device__ __forceinline__ bf16x8 pack8(f32x4 a, f32x4 b){
    union { unsigned u[4]; bf16x8 v; } r;
    r.u[0] = packbf(a[0], a[1]); r.u[1] = packbf(a[2], a[3]);
    r.u[2] = packbf(b[0], b[1]); r.u[3] = packbf(b[2], b[3]);
    return r.v;
}

// XOR-swizzled LDS index maps (shorts), 8-short (16B) granules.
// q/k/vT: 32 rows x 64 cols, stride 64. swz=(row^(row>>2))&7 spreads scalar
// writes (g-groups) across all 8 granule offsets -> 2-way max; b128 reads balanced.
#define QKSWZ(row, col) ((row) * 64 + ((col) ^ ((((row) ^ ((row) >> 2)) & 7) << 3)))
// ao: 32 rows x 512 cols, stride 512 (1KB rows == bank-aligned), row-XOR granule.
#define AOSWZ(row, col) ((row) * 512 + ((col) ^ (((row) & 7) << 3)))

// -------- prep: Wout transpose (blocks 0..31) + BN stats (blocks 32..1055) --------
__global__ __launch_bounds__(256) void prep_k(const float* __restrict__ Wout,
                                              const f32x4* __restrict__ x4,
                                              float* __restrict__ ws, int n4) {
    __shared__ __align__(16) unsigned char smem[8448];
    const int t = threadIdx.x;
    if (blockIdx.x < 32) {
        // ---- Wout[512][256] -> WoutT bf16 [256][512], 64x64 LDS tile
        unsigned short (*tile)[65] = (unsigned short (*)[65])smem;
        const int k0 = (blockIdx.x & 7) * 64, n0 = (blockIdx.x >> 3) * 64;
        #pragma unroll
        for (int i = 0; i < 16; ++i) {
            int e = t + 256 * i;
            int kk = e >> 6, nn = e & 63;
            tile[kk][nn] = f2bf(Wout[(k0 + kk) * DIM + n0 + nn]);
        }
        __syncthreads();
        unsigned short* wt = (unsigned short*)(ws + WS_WT);
        #pragma unroll
        for (int i = 0; i < 2; ++i) {
            int f = t + 256 * i;               // 0..511
            int nn = f >> 3, kc = f & 7;
            union { unsigned short s[8]; uint4 u; } pk;
            #pragma unroll
            for (int j = 0; j < 8; ++j) pk.s[j] = tile[kc * 8 + j][nn];
            *(uint4*)(wt + (size_t)(n0 + nn) * INNER + k0 + kc * 8) = pk.u;
        }
    } else {
        // ---- BN channel sums (float4, 4-deep ILP, banked atomics)
        f32x4 (*rs)[64]  = (f32x4 (*)[64])smem;
        f32x4 (*rss)[64] = (f32x4 (*)[64])(smem + 4096);
        const int bid = blockIdx.x - 32;            // 0..1023
        const int tid = bid * 256 + t;
        const int stride = 1024 * 256;
        f32x4 s  = {0.f, 0.f, 0.f, 0.f};
        f32x4 ss = {0.f, 0.f, 0.f, 0.f};
        int f = tid;
        const int nloop = n4 / (4 * stride);
        for (int i = 0; i < nloop; ++i) {
            f32x4 v0 = x4[f];
            f32x4 v1 = x4[f + stride];
            f32x4 v2 = x4[f + 2 * stride];
            f32x4 v3 = x4[f + 3 * stride];
            f += 4 * stride;
            s += v0; ss += v0 * v0;
            s += v1; ss += v1 * v1;
            s += v2; ss += v2 * v2;
            s += v3; ss += v3 * v3;
        }
        for (; f < n4; f += stride) { f32x4 v = x4[f]; s += v; ss += v * v; }
        int c4 = t & 63, wv = t >> 6;
        rs[wv][c4] = s; rss[wv][c4] = ss;
        __syncthreads();
        const float* rsf  = (const float*)rs;
        const float* rssf = (const float*)rss;
        int ch = t;                                 // channel = ch (flat view)
        float S = rsf[ch]  + rsf[256 + ch]  + rsf[512 + ch]  + rsf[768 + ch];
        float Q = rssf[ch] + rssf[256 + ch] + rssf[512 + ch] + rssf[768 + ch];
        int bank = (bid & 3) * 256;
        atomicAdd(&ws[WS_SUMB + bank + ch], S);
        atomicAdd(&ws[WS_SSQB + bank + ch], Q);
    }
}

// ------- BN finalize + fold into QKV weights/biases (coalesced, LDS-staged) --------
__global__ __launch_bounds__(256) void fold_k(const float* __restrict__ Wq,
                                              const float* __restrict__ Wk,
                                              const float* __restrict__ Wv,
                                              const float* __restrict__ gam,
                                              const float* __restrict__ bet,
                                              float* __restrict__ ws, float inv_n) {
    __shared__ float wl[64][33];
    __shared__ float scs[DPG], shs[DPG];
    const int m = blockIdx.x, h = blockIdx.y, t = threadIdx.x;
    const float* W = (m == 0 ? Wq : (m == 1 ? Wk : Wv)) + h * DH * DPG;
    if (t < DPG) {                             // per-head BN finalize (redundant x3, cheap)
        int c = h * DPG + t;
        float S = ws[WS_SUMB + c] + ws[WS_SUMB + 256 + c] + ws[WS_SUMB + 512 + c] + ws[WS_SUMB + 768 + c];
        float Q = ws[WS_SSQB + c] + ws[WS_SSQB + 256 + c] + ws[WS_SSQB + 512 + c] + ws[WS_SSQB + 768 + c];
        float mean = S * inv_n;
        float var  = Q * inv_n - mean * mean;
        float sc   = gam[c] * rsqrtf(var + EPS);
        scs[t] = sc;
        shs[t] = bet[c] - mean * sc;
    }
    #pragma unroll
    for (int i = 0; i < 8; ++i) {
        int e = t + 256 * i;               // 0..2047 coalesced
        wl[e >> 5][e & 31] = W[e];
    }
    __syncthreads();
    const float qsc = (m == 0) ? 0.125f : 1.f;   // dim_head^-0.5 folded into q
    unsigned short* wf = (unsigned short*)(ws + WS_WF) + (m * HEADS + h) * DH * DPG;
    {
        int o = t >> 2, c0 = (t & 3) * 8;
        union { unsigned short s[8]; uint4 u; } pk;
        #pragma unroll
        for (int j = 0; j < 8; ++j) pk.s[j] = f2bf(wl[o][c0 + j] * scs[c0 + j] * qsc);
        *(uint4*)(wf + o * DPG + c0) = pk.u;
    }
    if (t < DH) {
        float bias = 0.f;
        #pragma unroll
        for (int c = 0; c < DPG; ++c) bias += shs[c] * wl[t][c];
        ws[WS_QB + (m * HEADS + h) * DH + t] = bias * qsc;
    }
}

// ---------------- fused BN + QKV + attention + output GEMM (all MFMA) ----------------
// grid = npts (4096), block = 256 (4 waves). Wave w handles heads {w, w+4}.
// V computed AFTER dots/softmax so vT reuses k's LDS, probs reuse q's.
// LDS 32KB/block; launch_bounds min-waves 4 -> VGPR cap 128 (R5's min=5 capped at ~96
// and spilled av/oacc to scratch: +375MB HBM traffic, dur 210->272. Do not repeat.)
// MFMA 16x16x32: A/B frag lane&15 = row, lane>>4 = k-octet; D col=lane&15, row=(lane>>4)*4+reg.
__global__ __launch_bounds__(256, 4) void attn_fused(const float* __restrict__ x,
                                                     const float* __restrict__ ws,
                                                     const float* __restrict__ bout,
                                                     float* __restrict__ out) {
    __shared__ __align__(16) unsigned short lds[16384];   // 32768 B

    const int t = threadIdx.x;
    const int w = t >> 6, L = t & 63;
    const int lr = L & 15, g = L >> 4;
    const long long rb = (long long)blockIdx.x * KNB;

    unsigned short* qsm = lds + w * 2048;            // [32][64] swizzled; probs reuse
    unsigned short* ksm = lds + 8192 + w * 2048;     // [32][64] swizzled; vT reuses
    unsigned short* psm = qsm;
    unsigned short* vtm = ksm;                       // vT[o][j] as [o&31][(o>>5)*32+j]
    const unsigned short* wfb = (const unsigned short*)(ws + WS_WF);
    const unsigned short* WT  = (const unsigned short*)(ws + WS_WT);

    // preload x fragments for both head-slots (hides HBM latency under hs=0)
    bf16x8 xa[2][2];
    #pragma unroll
    for (int hs = 0; hs < 2; ++hs)
        #pragma unroll
        for (int it = 0; it < 2; ++it) {
            const float* xp = x + (rb + it * 16 + lr) * DIM + (w + hs * 4) * DPG + g * 8;
            xa[hs][it] = pack8(*(const f32x4*)xp, *(const f32x4*)(xp + 4));
        }

    unsigned av_pk[2][2][4][2];                      // av packed bf16: [hs][it][ot][r-pair]

    #pragma unroll
    for (int hs = 0; hs < 2; ++hs) {
        const int h = w + hs * 4;

        // ---- Q,K via MFMA (bias in acc init), store as [row][d] swizzled
        #pragma unroll
        for (int m = 0; m < 2; ++m) {
            unsigned short* dst = m ? ksm : qsm;
            #pragma unroll
            for (int ot = 0; ot < 4; ++ot) {
                const int o = ot * 16 + lr;
                bf16x8 wf = *(const bf16x8*)(wfb + ((m * HEADS + h) * DH + o) * DPG + g * 8);
                float bv = ws[WS_QB + (m * HEADS + h) * DH + o];
                #pragma unroll
                for (int it = 0; it < 2; ++it) {
                    f32x4 c = {bv, bv, bv, bv};
                    c = __builtin_amdgcn_mfma_f32_16x16x32_bf16(xa[hs][it], wf, c, 0, 0, 0);
                    unsigned u01 = packbf(c[0], c[1]);
                    unsigned u23 = packbf(c[2], c[3]);
                    const int r0 = it * 16 + g * 4;
                    dst[QKSWZ(r0 + 0, o)] = (unsigned short)u01;
                    dst[QKSWZ(r0 + 1, o)] = (unsigned short)(u01 >> 16);
                    dst[QKSWZ(r0 + 2, o)] = (unsigned short)u23;
                    dst[QKSWZ(r0 + 3, o)] = (unsigned short)(u23 >> 16);
                }
            }
        }

        // ---- dots = q @ k^T  (D: col = j, row = i)
        f32x4 dt[2][2];
        #pragma unroll
        for (int it = 0; it < 2; ++it)
            #pragma unroll
            for (int jt = 0; jt < 2; ++jt) dt[it][jt] = (f32x4){0.f, 0.f, 0.f, 0.f};
        #pragma unroll
        for (int ksp = 0; ksp < 2; ++ksp) {
            bf16x8 qa[2], kb[2];
            #pragma unroll
            for (int it = 0; it < 2; ++it)
                qa[it] = *(const bf16x8*)(qsm + QKSWZ(it * 16 + lr, ksp * 32 + g * 8));
            #pragma unroll
            for (int jt = 0; jt < 2; ++jt)
                kb[jt] = *(const bf16x8*)(ksm + QKSWZ(jt * 16 + lr, ksp * 32 + g * 8));
            #pragma unroll
            for (int it = 0; it < 2; ++it)
                #pragma unroll
                for (int jt = 0; jt < 2; ++jt)
                    dt[it][jt] = __builtin_amdgcn_mfma_f32_16x16x32_bf16(qa[it], kb[jt], dt[it][jt], 0, 0, 0);
        }

        // ---- softmax over j: local pair + xor-reduce across the 16-lane col group
        #pragma unroll
        for (int it = 0; it < 2; ++it)
            #pragma unroll
            for (int r = 0; r < 4; ++r) {
                float m0 = fmaxf(dt[it][0][r], dt[it][1][r]);
                m0 = fmaxf(m0, __shfl_xor(m0, 1, 64));
                m0 = fmaxf(m0, __shfl_xor(m0, 2, 64));
                m0 = fmaxf(m0, __shfl_xor(m0, 4, 64));
                m0 = fmaxf(m0, __shfl_xor(m0, 8, 64));
                float e0 = __expf(dt[it][0][r] - m0);
                float e1 = __expf(dt[it][1][r] - m0);
                float s = e0 + e1;
                s += __shfl_xor(s, 1, 64);
                s += __shfl_xor(s, 2, 64);
                s += __shfl_xor(s, 4, 64);
                s += __shfl_xor(s, 8, 64);
                float inv = 1.f / s;
                int row = it * 16 + g * 4 + r;
                unsigned up = packbf(e0 * inv, e1 * inv);
                psm[QKSWZ(row, lr)]      = (unsigned short)up;
                psm[QKSWZ(row, lr + 16)] = (unsigned short)(up >> 16);
            }

        // ---- V via MFMA (k dead after dots; xa still live) -> vT in ksm space
        #pragma unroll
        for (int ot = 0; ot < 4; ++ot) {
            const int o = ot * 16 + lr;
            bf16x8 wf = *(const bf16x8*)(wfb + ((2 * HEADS + h) * DH + o) * DPG + g * 8);
            float bv = ws[WS_QB + (2 * HEADS + h) * DH + o];
            #pragma unroll
            for (int it = 0; it < 2; ++it) {
                f32x4 c = {bv, bv, bv, bv};
                c = __builtin_amdgcn_mfma_f32_16x16x32_bf16(xa[hs][it], wf, c, 0, 0, 0);
                uint2 u;                      // vT[o][j..j+3]
                u.x = packbf(c[0], c[1]);
                u.y = packbf(c[2], c[3]);
                *(uint2*)(vtm + QKSWZ(o & 31, (o >> 5) * 32 + it * 16 + g * 4)) = u;
            }
        }

        // ---- AV: A = probs[i][j], B = vT[o][j]; pack result to bf16 immediately
        #pragma unroll
        for (int it = 0; it < 2; ++it) {
            bf16x8 pa = *(const bf16x8*)(psm + QKSWZ(it * 16 + lr, g * 8));
            #pragma unroll
            for (int ot = 0; ot < 4; ++ot) {
                bf16x8 vb = *(const bf16x8*)(vtm + QKSWZ((ot & 1) * 16 + lr, (ot >> 1) * 32 + g * 8));
                f32x4 c = {0.f, 0.f, 0.f, 0.f};
                c = __builtin_amdgcn_mfma_f32_16x16x32_bf16(pa, vb, c, 0, 0, 0);
                av_pk[hs][it][ot][0] = packbf(c[0], c[1]);
                av_pk[hs][it][ot][1] = packbf(c[2], c[3]);
            }
        }
    }

    // ---- gather full-point ao[32][512] in LDS (av_pk held in regs across barrier)
    __syncthreads();
    unsigned short* aos = lds;
    #pragma unroll
    for (int hs = 0; hs < 2; ++hs)
        #pragma unroll
        for (int it = 0; it < 2; ++it)
            #pragma unroll
            for (int ot = 0; ot < 4; ++ot) {
                unsigned u0 = av_pk[hs][it][ot][0];
                unsigned u1 = av_pk[hs][it][ot][1];
                const int colb = (w + hs * 4) * 64 + ot * 16 + lr;
                const int r0 = it * 16 + g * 4;
                aos[AOSWZ(r0 + 0, colb)] = (unsigned short)u0;
                aos[AOSWZ(r0 + 1, colb)] = (unsigned short)(u0 >> 16);
                aos[AOSWZ(r0 + 2, colb)] = (unsigned short)u1;
                aos[AOSWZ(r0 + 3, colb)] = (unsigned short)(u1 >> 16);
            }
    __syncthreads();

    // ---- output GEMM: out[32x256] = ao[32x512] @ WoutT^T + bout. Wave w: cols w*64..+63.
    f32x4 oacc[2][4];
    #pragma unroll
    for (int n4 = 0; n4 < 4; ++n4) {
        float bv = bout[(w * 4 + n4) * 16 + lr];
        oacc[0][n4] = (f32x4){bv, bv, bv, bv};
        oacc[1][n4] = (f32x4){bv, bv, bv, bv};
    }
    #pragma unroll 4
    for (int ksp = 0; ksp < 16; ++ksp) {
        bf16x8 a0 = *(const bf16x8*)(aos + AOSWZ(lr, ksp * 32 + g * 8));
        bf16x8 a1 = *(const bf16x8*)(aos + AOSWZ(16 + lr, ksp * 32 + g * 8));
        #pragma unroll
        for (int n4 = 0; n4 < 4; ++n4) {
            const int n = (w * 4 + n4) * 16 + lr;
            bf16x8 bvv = *(const bf16x8*)(WT + (size_t)n * INNER + ksp * 32 + g * 8);
            oacc[0][n4] = __builtin_amdgcn_mfma_f32_16x16x32_bf16(a0, bvv, oacc[0][n4], 0, 0, 0);
            oacc[1][n4] = __builtin_amdgcn_mfma_f32_16x16x32_bf16(a1, bvv, oacc[1][n4], 0, 0, 0);
        }
    }
    #pragma unroll
    for (int it = 0; it < 2; ++it)
        #pragma unroll
        for (int n4 = 0; n4 < 4; ++n4)
            #pragma unroll
            for (int r = 0; r < 4; ++r)
                out[(rb + it * 16 + g * 4 + r) * DIM + (w * 4 + n4) * 16 + lr] = oacc[it][n4][r];
}

extern "C" void kernel_launch(void* const* d_in, const int* in_sizes, int n_in,
                              void* d_out, int out_size, void* d_ws, size_t ws_size,
                              hipStream_t stream) {
    const float* x  = (const float*)d_in[0];
    const float* g  = (const float*)d_in[1];
    const float* b  = (const float*)d_in[2];
    const float* wq = (const float*)d_in[3];
    const float* wk = (const float*)d_in[4];
    const float* wv = (const float*)d_in[5];
    const float* wo = (const float*)d_in[6];
    const float* bo = (const float*)d_in[7];
    float* ws = (float*)d_ws;

    int rows = in_sizes[0] / DIM;       // 131072
    int npts = rows / KNB;              // 4096

    hipMemsetAsync(d_ws, 0, 8192, stream);
    prep_k<<<1056, 256, 0, stream>>>(wo, (const f32x4*)x, ws, rows * (DIM / 4));
    fold_k<<<dim3(3, HEADS), 256, 0, stream>>>(wq, wk, wv, g, b, ws, 1.0f / (float)rows);
    attn_fused<<<npts, 256, 0, stream>>>(x, ws, bo, (float*)d_out);
}